// Round 6
// baseline (327.202 us; speedup 1.0000x reference)
//
#include <hip/hip_runtime.h>
#include <hip/hip_bf16.h>

#define BATCH 4
#define CCH   256
#define NPOS  4096
#define NGRP  8
#define CPG   32
#define KVB   32
#define QB    128            // q rows per attn block (4 waves x 32)
#define NSPLIT 4
#define JLEN  (NPOS / NSPLIT)   // 1024
#define NITER (JLEN / KVB)      // 32

typedef __attribute__((ext_vector_type(8))) short bfx8;
typedef __attribute__((ext_vector_type(4))) short bfx4;
typedef __attribute__((ext_vector_type(4))) float f32x4;
typedef __attribute__((ext_vector_type(2))) unsigned int u32x2;
typedef __attribute__((ext_vector_type(4))) unsigned int u32x4;

__device__ __forceinline__ short f2bf(float f){
    unsigned u = __builtin_bit_cast(unsigned, f);
    u += 0x7fffu + ((u >> 16) & 1u);
    return (short)(u >> 16);
}
__device__ __forceinline__ float bf2f(short s){
    unsigned u = ((unsigned)(unsigned short)s) << 16;
    return __builtin_bit_cast(float, u);
}

typedef const __attribute__((address_space(1))) unsigned int* as1_u32p;
typedef __attribute__((address_space(3))) unsigned int* as3_u32p;

// async global->LDS, 16B/lane; LDS dest = wave-uniform base + lane*16 (linear).
__device__ __forceinline__ void async_cp16(short* lds, const short* g) {
    __builtin_amdgcn_global_load_lds((as1_u32p)(unsigned long long)g,
                                     (as3_u32p)(unsigned int)(unsigned long long)lds,
                                     16, 0, 0);
}

// ---------------------------------------------------------------------------
// GroupNorm stats (y<8) + W fp32->bf16 convert strip (y==8).
// grid (32, 9), 256 thr.
// ---------------------------------------------------------------------------
__global__ __launch_bounds__(256) void gn_stats(
    const float* __restrict__ x, float* __restrict__ psum,
    const float* __restrict__ Wq, const float* __restrict__ Wk,
    const float* __restrict__ Wv, const float* __restrict__ Wf,
    short* __restrict__ Wball)
{
    const int t = threadIdx.x;
    if (blockIdx.y == 8) {   // convert 4 W matrices; 8192 elems per block
        const int bx = blockIdx.x;
        const int m = bx >> 3;                       // 8 blocks per matrix
        const float* src = (m == 0) ? Wq : (m == 1) ? Wk : (m == 2) ? Wv : Wf;
        const int base = (bx & 7) * 8192;            // within matrix
        short* dst = Wball + m * 65536;
        #pragma unroll
        for (int it = 0; it < 4; it++) {
            const int idx = base + it * 2048 + t * 8;
            const float4 a = *(const float4*)&src[idx];
            const float4 b = *(const float4*)&src[idx + 4];
            bfx8 o = { f2bf(a.x), f2bf(a.y), f2bf(a.z), f2bf(a.w),
                       f2bf(b.x), f2bf(b.y), f2bf(b.z), f2bf(b.w) };
            *(bfx8*)&dst[idx] = o;
        }
        return;
    }
    const int bg = blockIdx.x, p = blockIdx.y;
    const size_t base = (size_t)bg * (CPG * NPOS) + (size_t)p * 16384;
    const float4* x4 = (const float4*)(x + base);
    float s = 0.f, s2 = 0.f;
    for (int i = t; i < 4096; i += 256) {
        float4 v = x4[i];
        s  += v.x + v.y + v.z + v.w;
        s2 += v.x*v.x + v.y*v.y + v.z*v.z + v.w*v.w;
    }
    for (int off = 32; off; off >>= 1) {
        s  += __shfl_down(s,  off);
        s2 += __shfl_down(s2, off);
    }
    __shared__ float rs[4], rs2[4];
    if ((t & 63) == 0) { rs[t >> 6] = s; rs2[t >> 6] = s2; }
    __syncthreads();
    if (t == 0) {
        psum[(bg*8 + p)*2 + 0] = rs[0] + rs[1] + rs[2] + rs[3];
        psum[(bg*8 + p)*2 + 1] = rs2[0] + rs2[1] + rs2[2] + rs2[3];
    }
}

// ---------------------------------------------------------------------------
// GroupNorm apply + transpose to position-major bf16 [B][N][C].
// grid (32 n-chunks, 32 bg), 256 thr.
// ---------------------------------------------------------------------------
__global__ __launch_bounds__(256) void gn_apply(
    const float* __restrict__ x, const float* __restrict__ gamma,
    const float* __restrict__ beta, const float* __restrict__ psum,
    short* __restrict__ xnb)
{
    const int ch = blockIdx.x, bg = blockIdx.y;
    const int b = bg >> 3, g = bg & 7;
    float S = 0.f, S2 = 0.f;
    #pragma unroll
    for (int p = 0; p < 8; p++) {
        S  += psum[(bg*8 + p)*2 + 0];
        S2 += psum[(bg*8 + p)*2 + 1];
    }
    const float inv = 1.0f / (float)(CPG * NPOS);
    const float mu = S * inv;
    const float rstd = rsqrtf(S2 * inv - mu * mu + 1e-5f);

    __shared__ float T[32][132];
    const int t = threadIdx.x;
    const int c = t >> 3;
    const int gc = g * CPG + c;
    const float ga = gamma[gc] * rstd;
    const float be = beta[gc] - mu * ga;
    const float* xr = &x[((size_t)b * CCH + gc) * NPOS + ch * 128];
    #pragma unroll
    for (int k = 0; k < 4; k++) {
        const int nl = (t & 7) * 16 + k * 4;
        float4 v = *(const float4*)&xr[nl];
        v.x = v.x * ga + be; v.y = v.y * ga + be;
        v.z = v.z * ga + be; v.w = v.w * ga + be;
        *(float4*)&T[c][nl] = v;
    }
    __syncthreads();
    const int n = t >> 1, hf = t & 1;
    short* orow = &xnb[((size_t)b * NPOS + ch * 128 + n) * CCH + g * CPG + hf * 16];
    bfx8 o0, o1;
    #pragma unroll
    for (int e = 0; e < 8; e++) {
        o0[e] = f2bf(T[hf*16 + e][n]);
        o1[e] = f2bf(T[hf*16 + 8 + e][n]);
    }
    *(bfx8*)&orow[0] = o0;
    *(bfx8*)&orow[8] = o1;
}

// ---------------------------------------------------------------------------
// bf16 MFMA GEMM. A = X [B][N][C] bf16, B = W bf16 [O][C]. Tile 64n x 128o,
// BK=64 double-buffered, 4 waves (wave tile 32n x 64o), 1 barrier/kstep.
// grid (64, 2, 4) = 512 blocks. XOR-swizzled LDS tiles.
// MODE 0: Yb bf16 [B][N][C] = (D + bias)*scale      (Q/K)
// MODE 1: Yb bf16 [B][C][N] = D + bias              (V)
// MODE 2: Yf fp32 [B][C][N] = D + bias + resid      (final)
// ---------------------------------------------------------------------------
template<int MODE>
__global__ __launch_bounds__(256, 2) void gemm_mfma(
    const short* __restrict__ Wg, const short* __restrict__ Xb,
    const float* __restrict__ bias, const float* __restrict__ resid,
    short* __restrict__ Yb, float* __restrict__ Yf, float scale)
{
    __shared__ short Xl[2][64 * 64];     // 8KB x2
    __shared__ short Wl[2][128 * 64];    // 16KB x2  -> 48KB total
    const int t = threadIdx.x, l = t & 63, w = t >> 6;
    const int lg = l >> 4, ln = l & 15;
    const int b = blockIdx.z;
    const int n0 = blockIdx.x * 64, o0 = blockIdx.y * 128;
    const int wn = (w >> 1) * 32, wo = (w & 1) * 64;
    const short* Xg = Xb + ((size_t)b * NPOS + n0) * CCH;

    f32x4 acc[2][4];
    #pragma unroll
    for (int i = 0; i < 2; i++)
        #pragma unroll
        for (int j = 0; j < 4; j++) acc[i][j] = (f32x4){0.f,0.f,0.f,0.f};

    bfx8 xs[2], ws4[4];
    auto GLOAD = [&](int kk) {
        #pragma unroll
        for (int i = 0; i < 2; i++) {
            const int L = i*256 + t;
            xs[i] = *(const bfx8*)&Xg[(size_t)(L>>3)*CCH + kk + (L&7)*8];
        }
        #pragma unroll
        for (int i = 0; i < 4; i++) {
            const int L = i*256 + t;
            ws4[i] = *(const bfx8*)&Wg[(size_t)(o0 + (L>>3))*CCH + kk + (L&7)*8];
        }
    };
    auto WRITE = [&](int buf) {
        #pragma unroll
        for (int i = 0; i < 2; i++) {
            const int L = i*256 + t; const int r = L>>3, c = (L&7)*8;
            *(bfx8*)&Xl[buf][r*64 + (c ^ ((r&7)<<3))] = xs[i];
        }
        #pragma unroll
        for (int i = 0; i < 4; i++) {
            const int L = i*256 + t; const int r = L>>3, c = (L&7)*8;
            *(bfx8*)&Wl[buf][r*64 + (c ^ ((r&7)<<3))] = ws4[i];
        }
    };

    GLOAD(0); WRITE(0); __syncthreads();
    int cur = 0;
    const int swz = (ln & 7) << 3;
    for (int step = 0; step < 4; step++) {
        if (step < 3) GLOAD((step + 1) * 64);
        #pragma unroll
        for (int k2 = 0; k2 < 2; k2++) {
            bfx8 xf[2], wf[4];
            const int cb = (k2*32 + lg*8) ^ swz;
            #pragma unroll
            for (int i = 0; i < 2; i++)
                xf[i] = *(const bfx8*)&Xl[cur][(wn + i*16 + ln)*64 + cb];
            #pragma unroll
            for (int j = 0; j < 4; j++)
                wf[j] = *(const bfx8*)&Wl[cur][(wo + j*16 + ln)*64 + cb];
            #pragma unroll
            for (int i = 0; i < 2; i++)
                #pragma unroll
                for (int j = 0; j < 4; j++) {
                    if constexpr (MODE == 0)
                        acc[i][j] = __builtin_amdgcn_mfma_f32_16x16x32_bf16(wf[j], xf[i], acc[i][j], 0,0,0);
                    else
                        acc[i][j] = __builtin_amdgcn_mfma_f32_16x16x32_bf16(xf[i], wf[j], acc[i][j], 0,0,0);
                }
        }
        if (step < 3) { WRITE(cur ^ 1); __syncthreads(); cur ^= 1; }
    }

    if constexpr (MODE == 0) {
        // D[o][n]: lane holds 4 consecutive o at fixed n -> b64 stores to [N][C]
        #pragma unroll
        for (int i = 0; i < 2; i++) {
            const int n = n0 + wn + i*16 + ln;
            short* dst = &Yb[((size_t)b * NPOS + n) * CCH + o0 + wo];
            #pragma unroll
            for (int j = 0; j < 4; j++) {
                const float4 bv = *(const float4*)&bias[o0 + wo + j*16 + lg*4];
                bfx4 pk = { f2bf((acc[i][j][0] + bv.x) * scale),
                            f2bf((acc[i][j][1] + bv.y) * scale),
                            f2bf((acc[i][j][2] + bv.z) * scale),
                            f2bf((acc[i][j][3] + bv.w) * scale) };
                *(bfx4*)&dst[j*16 + lg*4] = pk;
            }
        }
    } else {
        // D[n][o]: lane holds 4 consecutive n at fixed o -> stores to [C][N]
        #pragma unroll
        for (int j = 0; j < 4; j++) {
            const int o = o0 + wo + j*16 + ln;
            const float bv = bias[o];
            #pragma unroll
            for (int i = 0; i < 2; i++) {
                const size_t base = ((size_t)b * CCH + o) * NPOS + n0 + wn + i*16 + lg*4;
                if constexpr (MODE == 1) {
                    bfx4 pk = { f2bf(acc[i][j][0] + bv), f2bf(acc[i][j][1] + bv),
                                f2bf(acc[i][j][2] + bv), f2bf(acc[i][j][3] + bv) };
                    *(bfx4*)&Yb[base] = pk;
                } else {
                    const f32x4 rv = *(const f32x4*)&resid[base];
                    f32x4 v = acc[i][j];
                    v[0] += bv + rv[0]; v[1] += bv + rv[1];
                    v[2] += bv + rv[2]; v[3] += bv + rv[3];
                    *(f32x4*)&Yf[base] = v;
                }
            }
        }
    }
}

// ---------------------------------------------------------------------------
// MFMA flash attention. Q,K bf16 [B][N][C] (Q pre-scaled), V bf16 [B][C][N].
// 4 waves x 32 q = QB 128. K double-buffered via global_load_lds
// (pre-swizzled source, linear dest); V reg-staged (pad-40).
// PV operand-swapped: D[d][q=lane] -> lane-local softmax state + b64 stores.
// grid (32, NSPLIT=4, 4) = 512 blocks, 256 thr.
// ---------------------------------------------------------------------------
#define STAGE_K(BUF, J0) do { \
    short* kb_ = &Ks[BUF][0]; \
    _Pragma("unroll") \
    for (int i_ = 0; i_ < 4; i_++) { \
        const int L_ = i_*256 + t; \
        const int j_ = L_ >> 5; \
        const int c_ = ((L_ & 31) << 3) ^ ((j_ & 7) << 3); \
        async_cp16(&kb_[(i_*256 + (t & 192)) << 3], \
                   &Kg[(size_t)((J0) + j_) * CCH + c_]); \
    } \
} while (0)

// lane-local online softmax (q = ln). Defer-max THR=4.
#define SOFTMAX_MT(SA, SB, mreg, lreg, accA, paOut) do { \
    float tm_ = fmaxf(fmaxf(fmaxf(SA[0],SA[1]),fmaxf(SA[2],SA[3])), \
                      fmaxf(fmaxf(SB[0],SB[1]),fmaxf(SB[2],SB[3]))); \
    tm_ = fmaxf(tm_, __shfl_xor(tm_, 16)); \
    tm_ = fmaxf(tm_, __shfl_xor(tm_, 32)); \
    if (__any(tm_ > mreg + 4.0f)) { \
        const float mn_ = fmaxf(mreg, tm_); \
        const float al_ = __expf(mreg - mn_); \
        mreg = mn_; lreg *= al_; \
        _Pragma("unroll") \
        for (int dt_ = 0; dt_ < 16; dt_++) accA[dt_] *= al_; \
    } \
    const float p0_ = __expf(SA[0]-mreg), p1_ = __expf(SA[1]-mreg); \
    const float p2_ = __expf(SA[2]-mreg), p3_ = __expf(SA[3]-mreg); \
    const float p4_ = __expf(SB[0]-mreg), p5_ = __expf(SB[1]-mreg); \
    const float p6_ = __expf(SB[2]-mreg), p7_ = __expf(SB[3]-mreg); \
    float ps_ = ((p0_+p1_)+(p2_+p3_)) + ((p4_+p5_)+(p6_+p7_)); \
    ps_ += __shfl_xor(ps_, 16); ps_ += __shfl_xor(ps_, 32); \
    lreg += ps_; \
    paOut = (bfx8){ f2bf(p0_), f2bf(p1_), f2bf(p2_), f2bf(p3_), \
                    f2bf(p4_), f2bf(p5_), f2bf(p6_), f2bf(p7_) }; \
} while (0)

__global__ __launch_bounds__(256, 2) void attn_mfma(
    const short* __restrict__ Qt, const short* __restrict__ Kt,
    const short* __restrict__ Vc, short* __restrict__ Op0,
    short* __restrict__ Op123, float* __restrict__ Mp, float* __restrict__ Lp)
{
    __shared__ short Ks[2][KVB * 256];   // 16KB x2, XOR-swizzled layout
    __shared__ short Vt[256 * 40];       // 20KB, [d][j] pad-40

    const int t = threadIdx.x;
    const int l = t & 63, w = t >> 6;
    const int lg = l >> 4, ln = l & 15;
    const int h = blockIdx.y, b = blockIdx.z;
    const size_t bo = (size_t)b * NPOS * CCH;
    const short* Qg = Qt + bo;
    const short* Kg = Kt + bo;
    const short* Vg = Vc + bo;
    short* Op = (h == 0) ? Op0 : (Op123 + (size_t)(h - 1) * BATCH * NPOS * CCH);

    const int qbase = blockIdx.x * QB + w * 32;

    bfx8 qf0[8], qf1[8];
    #pragma unroll
    for (int kt = 0; kt < 8; kt++) {
        qf0[kt] = *(const bfx8*)&Qg[(size_t)(qbase + ln) * CCH + kt*32 + lg*8];
        qf1[kt] = *(const bfx8*)&Qg[(size_t)(qbase + 16 + ln) * CCH + kt*32 + lg*8];
    }

    f32x4 acc0[16], acc1[16];
    #pragma unroll
    for (int dt = 0; dt < 16; dt++) {
        acc0[dt] = (f32x4){0.f,0.f,0.f,0.f};
        acc1[dt] = (f32x4){0.f,0.f,0.f,0.f};
    }
    float m0 = -1e30f, l0 = 0.f, m1 = -1e30f, l1 = 0.f;
    const int j0base = h * JLEN;

    // prologue: stage tile 0 (K -> LDS buf0, V -> regs -> Vt)
    {
        STAGE_K(0, j0base);
        bfx8 vld[4];
        #pragma unroll
        for (int i = 0; i < 4; i++) {
            const int L = i*256 + t;
            vld[i] = *(const bfx8*)&Vg[(size_t)(L>>2) * NPOS + j0base + (L&3)*8];
        }
        #pragma unroll
        for (int i = 0; i < 4; i++) {
            const int L = i*256 + t;
            *(bfx8*)&Vt[(L>>2) * 40 + (L&3)*8] = vld[i];
        }
        __syncthreads();
    }

    int cur = 0;
    for (int s = 0; s < NITER; s++) {
        const int j0n = j0base + (s + 1) * KVB;
        bfx8 vld[4];
        if (s + 1 < NITER) {
            STAGE_K(cur ^ 1, j0n);            // async into other buffer
            #pragma unroll
            for (int i = 0; i < 4; i++) {
                const int L = i*256 + t;
                vld[i] = *(const bfx8*)&Vg[(size_t)(L>>2) * NPOS + j0n + (L&3)*8];
            }
        }

        // QK^T (swapped): S[j][q], A = K rows j, B = Q cols q=ln
        const short* bK = &Ks[cur][0];
        f32x4 S00 = (f32x4){0,0,0,0}, S01 = (f32x4){0,0,0,0};
        f32x4 S10 = (f32x4){0,0,0,0}, S11 = (f32x4){0,0,0,0};
        #pragma unroll
        for (int kt = 0; kt < 8; kt++) {
            const int cA = (kt*32 + lg*8) ^ ((ln & 7) << 3);
            const bfx8 kf0 = *(const bfx8*)&bK[ln * 256 + cA];
            const bfx8 kf1 = *(const bfx8*)&bK[(16 + ln) * 256 + cA];
            S00 = __builtin_amdgcn_mfma_f32_16x16x32_bf16(kf0, qf0[kt], S00, 0,0,0);
            S01 = __builtin_amdgcn_mfma_f32_16x16x32_bf16(kf1, qf0[kt], S01, 0,0,0);
            S10 = __builtin_amdgcn_mfma_f32_16x16x32_bf16(kf0, qf1[kt], S10, 0,0,0);
            S11 = __builtin_amdgcn_mfma_f32_16x16x32_bf16(kf1, qf1[kt], S11, 0,0,0);
        }

        // softmax, P packed in-register; pi(lg,e) = lg*4+(e&3)+16*(e>>2)
        bfx8 pa0, pa1;
        SOFTMAX_MT(S00, S01, m0, l0, acc0, pa0);
        SOFTMAX_MT(S10, S11, m1, l1, acc1, pa1);

        // PV swapped: A = V (row d = ln-based), B = P (col q = ln) -> D[d][q]
        #pragma unroll
        for (int dt = 0; dt < 16; dt++) {
            const int d = dt*16 + ln;
            const u32x2 v0 = *(const u32x2*)&Vt[d * 40 + lg*4];
            const u32x2 v1 = *(const u32x2*)&Vt[d * 40 + 16 + lg*4];
            const bfx8 vf = __builtin_bit_cast(bfx8, (u32x4){ v0[0], v0[1], v1[0], v1[1] });
            acc0[dt] = __builtin_amdgcn_mfma_f32_16x16x32_bf16(vf, pa0, acc0[dt], 0,0,0);
            acc1[dt] = __builtin_amdgcn_mfma_f32_16x16x32_bf16(vf, pa1, acc1[dt], 0,0,0);
        }

        __syncthreads();                      // all waves done reading Vt
        if (s + 1 < NITER) {
            #pragma unroll
            for (int i = 0; i < 4; i++) {
                const int L = i*256 + t;
                *(bfx8*)&Vt[(L>>2) * 40 + (L&3)*8] = vld[i];
            }
        }
        __syncthreads();                      // Vt(s+1) + Ks[cur^1] ready
        cur ^= 1;
    }

    // epilogue: lane-local normalize (q = ln), b64 stores
    {
        const float inv0 = 1.0f / l0;
        short* orow = &Op[((size_t)b * NPOS + qbase + ln) * CCH];
        #pragma unroll
        for (int dt = 0; dt < 16; dt++) {
            const f32x4 o = acc0[dt] * inv0;
            bfx4 pk = { f2bf(o[0]), f2bf(o[1]), f2bf(o[2]), f2bf(o[3]) };
            *(bfx4*)&orow[dt*16 + lg*4] = pk;
        }
        if (lg == 0) {
            Mp[((size_t)h * BATCH + b) * NPOS + qbase + ln] = m0;
            Lp[((size_t)h * BATCH + b) * NPOS + qbase + ln] = l0;
        }
    }
    {
        const float inv1 = 1.0f / l1;
        short* orow = &Op[((size_t)b * NPOS + qbase + 16 + ln) * CCH];
        #pragma unroll
        for (int dt = 0; dt < 16; dt++) {
            const f32x4 o = acc1[dt] * inv1;
            bfx4 pk = { f2bf(o[0]), f2bf(o[1]), f2bf(o[2]), f2bf(o[3]) };
            *(bfx4*)&orow[dt*16 + lg*4] = pk;
        }
        if (lg == 0) {
            Mp[((size_t)h * BATCH + b) * NPOS + qbase + 16 + ln] = m1;
            Lp[((size_t)h * BATCH + b) * NPOS + qbase + 16 + ln] = l1;
        }
    }
}

// ---------------------------------------------------------------------------
// Combine 4 normalized split-partials -> AO bf16 [B][N][C].
// grid (64, 4), 256 thr.
// ---------------------------------------------------------------------------
__global__ __launch_bounds__(256) void combine4(
    const short* __restrict__ Op0, const short* __restrict__ Op123,
    const float* __restrict__ Mp, const float* __restrict__ Lp,
    short* __restrict__ AO)
{
    const int b  = blockIdx.y;
    const int q0 = blockIdx.x * 64;
    const int t  = threadIdx.x;
    __shared__ float wgt[4][64];
    if (t < 64) {
        const size_t qi = (size_t)b * NPOS + q0 + t;
        float mm[4], ll[4];
        #pragma unroll
        for (int hh = 0; hh < 4; hh++) {
            mm[hh] = Mp[(size_t)hh * BATCH * NPOS + qi];
            ll[hh] = Lp[(size_t)hh * BATCH * NPOS + qi];
        }
        const float M = fmaxf(fmaxf(mm[0], mm[1]), fmaxf(mm[2], mm[3]));
        float e[4], sum = 0.f;
        #pragma unroll
        for (int hh = 0; hh < 4; hh++) { e[hh] = __expf(mm[hh] - M) * ll[hh]; sum += e[hh]; }
        const float invs = 1.0f / sum;
        #pragma unroll
        for (int hh = 0; hh < 4; hh++) wgt[hh][t] = e[hh] * invs;
    }
    __syncthreads();
    const size_t hs = (size_t)BATCH * NPOS * CCH;
    #pragma unroll
    for (int i = 0; i < 8; i++) {
        const int flat = i * 256 + t;
        const int q = flat >> 5;
        const int cb = (flat & 31) * 8;
        const size_t row = ((size_t)b * NPOS + q0 + q) * CCH + cb;
        const float w0 = wgt[0][q], w1 = wgt[1][q], w2 = wgt[2][q], w3 = wgt[3][q];
        const bfx8 a0 = *(const bfx8*)&Op0[row];
        const bfx8 a1 = *(const bfx8*)&Op123[row];
        const bfx8 a2 = *(const bfx8*)&Op123[hs + row];
        const bfx8 a3 = *(const bfx8*)&Op123[2*hs + row];
        bfx8 ov;
        #pragma unroll
        for (int e = 0; e < 8; e++)
            ov[e] = f2bf(w0*bf2f(a0[e]) + w1*bf2f(a1[e]) + w2*bf2f(a2[e]) + w3*bf2f(a3[e]));
        *(bfx8*)&AO[row] = ov;
    }
}

// ---------------------------------------------------------------------------
extern "C" void kernel_launch(void* const* d_in, const int* in_sizes, int n_in,
                              void* d_out, int out_size, void* d_ws, size_t ws_size,
                              hipStream_t stream)
{
    const float* x   = (const float*)d_in[0];
    const float* gns = (const float*)d_in[1];
    const float* gnb = (const float*)d_in[2];
    const float* Wq  = (const float*)d_in[3];
    const float* bq  = (const float*)d_in[4];
    const float* Wk  = (const float*)d_in[5];
    const float* bk  = (const float*)d_in[6];
    const float* Wv  = (const float*)d_in[7];
    const float* bv  = (const float*)d_in[8];
    const float* Wf  = (const float*)d_in[9];
    const float* bf  = (const float*)d_in[10];
    float* out = (float*)d_out;
    char* wsb  = (char*)d_ws;

    // workspace map (<= ~57.3 MB)
    short* xnb   = (short*)(wsb);                       // [0, 8M)   bf16 [B][N][C]
    short* Op0   = (short*)(wsb);                       // alias (xnb dead post-QKV)
    short* Qt    = (short*)(wsb + (8u  << 20));         // [8, 16M)
    short* Kt    = (short*)(wsb + (16u << 20));         // [16, 24M)
    short* Vc    = (short*)(wsb + (24u << 20));         // [24, 32M) bf16 [B][C][N]
    short* Op123 = (short*)(wsb + (32u << 20));         // [32, 56M)
    short* Wball = (short*)(wsb + (56u << 20));         // 512KB bf16 weights
    float* Mp    = (float*)(wsb + (56u << 20) + (512u << 10));
    float* Lp    = Mp + (size_t)NSPLIT * BATCH * NPOS;  // 256KB each
    float* psum  = Lp + (size_t)NSPLIT * BATCH * NPOS;  // 2KB
    short* AO    = Qt;                                  // alias (Qt dead post-attn)

    const short* Wqb = Wball;
    const short* Wkb = Wball + 65536;
    const short* Wvb = Wball + 131072;
    const short* Wfb = Wball + 196608;

    gn_stats<<<dim3(BATCH * NGRP, 9), 256, 0, stream>>>(x, psum, Wq, Wk, Wv, Wf, Wball);
    gn_apply<<<dim3(NPOS / 128, BATCH * NGRP), 256, 0, stream>>>(x, gns, gnb, psum, xnb);

    dim3 gg(NPOS / 64, CCH / 128, BATCH);
    gemm_mfma<0><<<gg, 256, 0, stream>>>(Wqb, xnb, bq, nullptr, Qt, nullptr, 0.0625f);
    gemm_mfma<0><<<gg, 256, 0, stream>>>(Wkb, xnb, bk, nullptr, Kt, nullptr, 1.f);
    gemm_mfma<1><<<gg, 256, 0, stream>>>(Wvb, xnb, bv, nullptr, Vc, nullptr, 1.f);

    attn_mfma<<<dim3(NPOS / QB, NSPLIT, BATCH), 256, 0, stream>>>(
        Qt, Kt, Vc, Op0, Op123, Mp, Lp);

    combine4<<<dim3(NPOS / 64, BATCH), 256, 0, stream>>>(Op0, Op123, Mp, Lp, AO);

    gemm_mfma<2><<<gg, 256, 0, stream>>>(Wfb, AO, bf, x, nullptr, out, 1.f);
}